// Round 3
// baseline (214.012 us; speedup 1.0000x reference)
//
#include <hip/hip_runtime.h>

#define NN 4096
#define IND 128
#define OUTD 64
#define LOG2E 1.44269504088896340736f

typedef __attribute__((ext_vector_type(4))) float  floatx4;
typedef __attribute__((ext_vector_type(8))) __bf16 bf16x8;
typedef __attribute__((ext_vector_type(2))) unsigned long long u64x2;

#if __has_builtin(__builtin_amdgcn_exp2f)
#define EXP2(x) __builtin_amdgcn_exp2f(x)
#else
#define EXP2(x) exp2f(x)
#endif

__device__ __forceinline__ unsigned short f2bf(float f) {
  unsigned int u = __float_as_uint(f);
  u += 0x7fffu + ((u >> 16) & 1u);   // RNE; inputs are finite
  return (unsigned short)(u >> 16);
}

// ---------------- Kernel 0: bitpack A -> bits[2][NN][64] u64, bit l of word w = A[i][w*64+l]
// Coalesced streaming read of A (the unavoidable 134 MB at HBM floor).
__global__ __launch_bounds__(256) void gat_pack(
    const int* __restrict__ A0, const int* __restrict__ A1,
    unsigned long long* __restrict__ bits)
{
  const int t    = threadIdx.x;
  const int lane = t & 63;
  const int wv   = t >> 6;
  const int unit = blockIdx.x * 4 + wv;      // 32768 units = (rel, i, quarter)
  const int q    = unit & 3;                 // j-base = q*1024
  const int i    = (unit >> 2) & (NN - 1);
  const int rel  = unit >> 14;
  const int* __restrict__ A = (rel ? A1 : A0) + (size_t)i * NN + q * 1024 + lane;

  unsigned long long wbuf[16];
#pragma unroll
  for (int k = 0; k < 16; k++)
    wbuf[k] = __ballot(A[k * 64] != 0);      // word k covers j=[q*1024+64k, +64), bit=lane

  if (lane == 0) {
    u64x2* dst = (u64x2*)(bits + ((size_t)rel * NN + i) * 64 + q * 16);
#pragma unroll
    for (int k = 0; k < 8; k++) {
      u64x2 v; v[0] = wbuf[2 * k]; v[1] = wbuf[2 * k + 1];
      dst[k] = v;
    }
  }
}

// ---------------- Kernel 1: Wh = H@W (fp32), s_a/s_b (pre-scaled by log2e), WhT bf16
__global__ __launch_bounds__(256) void gat_prep(
    const float* __restrict__ H,
    const float* __restrict__ W0, const float* __restrict__ W1,
    const float* __restrict__ av0, const float* __restrict__ av1,
    unsigned short* __restrict__ whT,   // [2][64][4096] bf16 bits (c-major)
    float* __restrict__ sA,             // [2][4096]  (log2e-scaled)
    float* __restrict__ sB)             // [2][4096]  (log2e-scaled)
{
  const int rel = blockIdx.y;
  const float* __restrict__ W  = rel ? W1 : W0;
  const float* __restrict__ av = rel ? av1 : av0;
  const int i0 = blockIdx.x * 16;
  const int t = threadIdx.x;
  const int c = t & 63;                                   // lane == output channel
  const int wv = __builtin_amdgcn_readfirstlane(t >> 6);  // wave -> 4 rows
  const float* __restrict__ hp = H + (size_t)(i0 + wv * 4) * IND;

  float acc0 = 0.f, acc1 = 0.f, acc2 = 0.f, acc3 = 0.f;
#pragma unroll 8
  for (int k = 0; k < IND; k += 4) {
    float4 h0 = *(const float4*)(hp + k);
    float4 h1 = *(const float4*)(hp + IND + k);
    float4 h2 = *(const float4*)(hp + 2 * IND + k);
    float4 h3 = *(const float4*)(hp + 3 * IND + k);
    float w0 = W[(k + 0) * OUTD + c];
    float w1 = W[(k + 1) * OUTD + c];
    float w2 = W[(k + 2) * OUTD + c];
    float w3 = W[(k + 3) * OUTD + c];
    acc0 += h0.x * w0 + h0.y * w1 + h0.z * w2 + h0.w * w3;
    acc1 += h1.x * w0 + h1.y * w1 + h1.z * w2 + h1.w * w3;
    acc2 += h2.x * w0 + h2.y * w1 + h2.z * w2 + h2.w * w3;
    acc3 += h3.x * w0 + h3.y * w1 + h3.z * w2 + h3.w * w3;
  }

  // s_a = Wh . a[:64]*log2e, s_b = Wh . a[64:]*log2e (wave reduction)
  const float alo = av[c] * LOG2E, ahi = av[OUTD + c] * LOG2E;
  float pa0 = acc0 * alo, pa1 = acc1 * alo, pa2 = acc2 * alo, pa3 = acc3 * alo;
  float pb0 = acc0 * ahi, pb1 = acc1 * ahi, pb2 = acc2 * ahi, pb3 = acc3 * ahi;
#pragma unroll
  for (int off = 32; off >= 1; off >>= 1) {
    pa0 += __shfl_xor(pa0, off); pa1 += __shfl_xor(pa1, off);
    pa2 += __shfl_xor(pa2, off); pa3 += __shfl_xor(pa3, off);
    pb0 += __shfl_xor(pb0, off); pb1 += __shfl_xor(pb1, off);
    pb2 += __shfl_xor(pb2, off); pb3 += __shfl_xor(pb3, off);
  }
  const int ibase = i0 + wv * 4;
  if (c == 0) {
    float* sa = sA + rel * NN + ibase;
    float* sb = sB + rel * NN + ibase;
    sa[0] = pa0; sa[1] = pa1; sa[2] = pa2; sa[3] = pa3;
    sb[0] = pb0; sb[1] = pb1; sb[2] = pb2; sb[3] = pb3;
  }

  unsigned long long packed =
      (unsigned long long)f2bf(acc0)        | ((unsigned long long)f2bf(acc1) << 16) |
      ((unsigned long long)f2bf(acc2) << 32) | ((unsigned long long)f2bf(acc3) << 48);
  *(unsigned long long*)(whT + (size_t)(rel * OUTD + c) * NN + ibase) = packed;
}

// ---------------- Kernel 2: masked-softmax matmul via MFMA. A-mask comes from
// preloaded bitmask registers — NO A traffic in the K-loop.
__global__ __launch_bounds__(512) void gat_main(
    const unsigned long long* __restrict__ bits,
    const unsigned short* __restrict__ whT,
    const float* __restrict__ sA, const float* __restrict__ sB,
    float* __restrict__ numer,          // [2][ns][4096][64]
    float* __restrict__ denom,          // [2][ns][4096]
    int ns)
{
  __shared__ float red[8][1024];
  __shared__ float dred[8][16];
  const int rel  = blockIdx.y;
  const int sp   = blockIdx.z;
  const int i0   = blockIdx.x * 16;
  const int t    = threadIdx.x;
  const int w    = t >> 6;
  const int lane = t & 63;
  const int m    = lane & 15;           // MFMA A-frag row
  const int quad = lane >> 4;           // MFMA k-slot group
  const int i    = i0 + m;
  const float si = sA[rel * NN + i];
  const float* __restrict__ sb = sB + rel * NN;
  const unsigned short* __restrict__ wh = whT + (size_t)rel * OUTD * NN;
  const unsigned long long* __restrict__ bp = bits + ((size_t)rel * NN + i) * 64;

  const int jwin = NN / (ns * 8);       // 512 (ns=1) or 256 (ns=2)
  const int jw0  = sp * (NN / ns) + w * jwin;
  const int nch  = jwin >> 8;           // 2 or 1 chunks of 256 j

  floatx4 acc0 = {0.f, 0.f, 0.f, 0.f}, acc1 = acc0, acc2 = acc0, acc3 = acc0;
  float dsum = 0.f;

  for (int c2 = 0; c2 < nch; c2++) {
    const int jc = jw0 + c2 * 256;
    // whole 256-j mask window for row i: 4 u64 in registers
    u64x2 bA = *(const u64x2*)(bp + (jc >> 6));
    u64x2 bB = *(const u64x2*)(bp + (jc >> 6) + 2);
    const float*          psb = sb + jc + quad * 8;
    const unsigned short* pb0 = wh + (size_t)(0 * 16 + m) * NN + jc + quad * 8;
    const unsigned short* pb1 = wh + (size_t)(1 * 16 + m) * NN + jc + quad * 8;
    const unsigned short* pb2 = wh + (size_t)(2 * 16 + m) * NN + jc + quad * 8;
    const unsigned short* pb3 = wh + (size_t)(3 * 16 + m) * NN + jc + quad * 8;

#pragma unroll
    for (int jt = 0; jt < 256; jt += 32) {
      float4 s0 = *(const float4*)(psb + jt);
      float4 s1 = *(const float4*)(psb + jt + 4);
      bf16x8 b0 = *(const bf16x8*)(pb0 + jt);
      bf16x8 b1 = *(const bf16x8*)(pb1 + jt);
      bf16x8 b2 = *(const bf16x8*)(pb2 + jt);
      bf16x8 b3 = *(const bf16x8*)(pb3 + jt);

      // static word select (jt is a constant under full unroll)
      const unsigned long long wbits =
          (jt < 64) ? bA[0] : (jt < 128) ? bA[1] : (jt < 192) ? bB[0] : bB[1];
      const unsigned bmask = (unsigned)(wbits >> ((jt & 63) + quad * 8)) & 0xFFu;

      float t0 = si + s0.x, t1 = si + s0.y, t2 = si + s0.z, t3 = si + s0.w;
      float t4 = si + s1.x, t5 = si + s1.y, t6 = si + s1.z, t7 = si + s1.w;
      float e0 = EXP2(fmaxf(t0, 0.2f * t0));
      float e1 = EXP2(fmaxf(t1, 0.2f * t1));
      float e2 = EXP2(fmaxf(t2, 0.2f * t2));
      float e3 = EXP2(fmaxf(t3, 0.2f * t3));
      float e4 = EXP2(fmaxf(t4, 0.2f * t4));
      float e5 = EXP2(fmaxf(t5, 0.2f * t5));
      float e6 = EXP2(fmaxf(t6, 0.2f * t6));
      float e7 = EXP2(fmaxf(t7, 0.2f * t7));
      e0 = (bmask & 1u)   ? e0 : 0.f;
      e1 = (bmask & 2u)   ? e1 : 0.f;
      e2 = (bmask & 4u)   ? e2 : 0.f;
      e3 = (bmask & 8u)   ? e3 : 0.f;
      e4 = (bmask & 16u)  ? e4 : 0.f;
      e5 = (bmask & 32u)  ? e5 : 0.f;
      e6 = (bmask & 64u)  ? e6 : 0.f;
      e7 = (bmask & 128u) ? e7 : 0.f;
      dsum += ((e0 + e1) + (e2 + e3)) + ((e4 + e5) + (e6 + e7));

      bf16x8 af;
      af[0] = (__bf16)e0; af[1] = (__bf16)e1; af[2] = (__bf16)e2; af[3] = (__bf16)e3;
      af[4] = (__bf16)e4; af[5] = (__bf16)e5; af[6] = (__bf16)e6; af[7] = (__bf16)e7;

      acc0 = __builtin_amdgcn_mfma_f32_16x16x32_bf16(af, b0, acc0, 0, 0, 0);
      acc1 = __builtin_amdgcn_mfma_f32_16x16x32_bf16(af, b1, acc1, 0, 0, 0);
      acc2 = __builtin_amdgcn_mfma_f32_16x16x32_bf16(af, b2, acc2, 0, 0, 0);
      acc3 = __builtin_amdgcn_mfma_f32_16x16x32_bf16(af, b3, acc3, 0, 0, 0);
    }
  }

  dsum += __shfl_xor(dsum, 16);
  dsum += __shfl_xor(dsum, 32);

  // C/D layout: col = lane&15 (+16*nt), row = quad*4 + reg   [m89/m91]
#pragma unroll
  for (int r = 0; r < 4; r++) {
    const int row = quad * 4 + r;
    red[w][row * 64 + 0 * 16 + m] = acc0[r];
    red[w][row * 64 + 1 * 16 + m] = acc1[r];
    red[w][row * 64 + 2 * 16 + m] = acc2[r];
    red[w][row * 64 + 3 * 16 + m] = acc3[r];
  }
  if (lane < 16) dred[w][lane] = dsum;
  __syncthreads();

  const int c  = t & 63;
  const int r0 = t >> 6;
  const size_t base = ((size_t)rel * ns + sp) * NN;
#pragma unroll
  for (int rr = r0; rr < 16; rr += 8) {
    float nsum = 0.f, ds = 0.f;
#pragma unroll
    for (int ww = 0; ww < 8; ww++) { nsum += red[ww][rr * 64 + c]; ds += dred[ww][rr]; }
    numer[(base + i0 + rr) * OUTD + c] = nsum;
    if (c == 0) denom[base + i0 + rr] = ds;
  }
}

// ---------------- Kernel 3: out = sum_rel( sum_sp(n) / sum_sp(d) ) + bias
__global__ __launch_bounds__(256) void gat_combine(
    const float* __restrict__ numer, const float* __restrict__ denom,
    const float* __restrict__ bias, float* __restrict__ out, int ns)
{
  const int idx = blockIdx.x * 256 + threadIdx.x;  // float4 index, 65536 total
  const int i  = idx >> 4;
  const int c4 = idx & 15;
  const float4* nv = (const float4*)numer;

  float4 o = ((const float4*)bias)[c4];
#pragma unroll
  for (int rel = 0; rel < 2; rel++) {
    float4 n = {0.f, 0.f, 0.f, 0.f};
    float  d = 0.f;
    for (int s = 0; s < ns; s++) {
      const size_t base = ((size_t)rel * ns + s) * NN + i;
      float4 np = nv[base * 16 + c4];
      n.x += np.x; n.y += np.y; n.z += np.z; n.w += np.w;
      d += denom[base];
    }
    float inv = d > 0.f ? 1.f / d : 0.f;   // isolated-row nan_to_num -> 0
    o.x += n.x * inv; o.y += n.y * inv; o.z += n.z * inv; o.w += n.w * inv;
  }
  ((float4*)out)[idx] = o;
}

extern "C" void kernel_launch(void* const* d_in, const int* in_sizes, int n_in,
                              void* d_out, int out_size, void* d_ws, size_t ws_size,
                              hipStream_t stream) {
  const float* H    = (const float*)d_in[0];
  const int*   A0   = (const int*)d_in[1];
  const int*   A1   = (const int*)d_in[2];
  const float* W0   = (const float*)d_in[3];
  const float* W1   = (const float*)d_in[4];
  const float* av0  = (const float*)d_in[5];
  const float* av1  = (const float*)d_in[6];
  const float* bias = (const float*)d_in[7];
  float* out = (float*)d_out;

  // ws layout: whT 1 MB | sA 32 KB | sB 32 KB | bits 4 MB | numer | denom
  const size_t whT_b = (size_t)2 * OUTD * NN * 2;        // 1 MB
  const size_t s_b   = (size_t)2 * NN * 4;               // 32 KB each
  const size_t bit_b = (size_t)2 * NN * 64 * 8;          // 4 MB
  // ns=2 needs whT+2s+bits+numer(8MB)+denom(128KB) ~= 13.8 MB; ns=1 ~= 9.6 MB
  const size_t need2 = whT_b + 2 * s_b + bit_b + (size_t)2 * 2 * NN * OUTD * 4 + (size_t)2 * 2 * NN * 4;
  const int ns = (ws_size >= need2) ? 2 : 1;

  unsigned short*     whT  = (unsigned short*)d_ws;
  float*              sA   = (float*)((char*)d_ws + whT_b);
  float*              sB   = (float*)((char*)d_ws + whT_b + s_b);
  unsigned long long* bits = (unsigned long long*)((char*)d_ws + whT_b + 2 * s_b);
  float*              numer = (float*)((char*)d_ws + whT_b + 2 * s_b + bit_b);
  float*              denom = numer + (size_t)2 * ns * NN * OUTD;

  gat_pack<<<8192, 256, 0, stream>>>(A0, A1, bits);
  gat_prep<<<dim3(NN / 16, 2), 256, 0, stream>>>(H, W0, W1, av0, av1, whT, sA, sB);
  gat_main<<<dim3(NN / 16, 2, ns), 512, 0, stream>>>(bits, whT, sA, sB, numer, denom, ns);
  gat_combine<<<(NN * OUTD / 4) / 256, 256, 0, stream>>>(numer, denom, bias, out, ns);
}

// Round 4
// 187.830 us; speedup vs baseline: 1.1394x; 1.1394x over previous
//
#include <hip/hip_runtime.h>

#define NN 4096
#define IND 128
#define OUTD 64
#define LOG2E 1.44269504088896340736f

typedef __attribute__((ext_vector_type(4))) float  floatx4;
typedef __attribute__((ext_vector_type(8))) __bf16 bf16x8;

#if __has_builtin(__builtin_amdgcn_exp2f)
#define EXP2(x) __builtin_amdgcn_exp2f(x)
#else
#define EXP2(x) exp2f(x)
#endif

__device__ __forceinline__ unsigned short f2bf(float f) {
  unsigned int u = __float_as_uint(f);
  u += 0x7fffu + ((u >> 16) & 1u);   // RNE; inputs are finite
  return (unsigned short)(u >> 16);
}

// ---------------- Kernel 1: Wh = H@W (fp32), s_a/s_b (log2e-scaled), whF bf16.
// whF is FRAGMENT-MAJOR: element (node j, channel c) at ((rel*512 + (j>>3))*64 + c)*8 + (j&7)
// so a gat_fused wave's B-fragment load is lane-contiguous (1 KB / instruction).
__global__ __launch_bounds__(256) void gat_prep(
    const float* __restrict__ H,
    const float* __restrict__ W0, const float* __restrict__ W1,
    const float* __restrict__ av0, const float* __restrict__ av1,
    unsigned short* __restrict__ whF,
    float* __restrict__ sA, float* __restrict__ sB)
{
  const int rel = blockIdx.y;
  const float* __restrict__ W  = rel ? W1 : W0;
  const float* __restrict__ av = rel ? av1 : av0;
  const int i0 = blockIdx.x * 16;
  const int t = threadIdx.x;
  const int c = t & 63;                                   // lane == output channel
  const int wv = __builtin_amdgcn_readfirstlane(t >> 6);  // wave -> 4 rows
  const float* __restrict__ hp = H + (size_t)(i0 + wv * 4) * IND;

  float acc0 = 0.f, acc1 = 0.f, acc2 = 0.f, acc3 = 0.f;
#pragma unroll 8
  for (int k = 0; k < IND; k += 4) {
    float4 h0 = *(const float4*)(hp + k);
    float4 h1 = *(const float4*)(hp + IND + k);
    float4 h2 = *(const float4*)(hp + 2 * IND + k);
    float4 h3 = *(const float4*)(hp + 3 * IND + k);
    float w0 = W[(k + 0) * OUTD + c];
    float w1 = W[(k + 1) * OUTD + c];
    float w2 = W[(k + 2) * OUTD + c];
    float w3 = W[(k + 3) * OUTD + c];
    acc0 += h0.x * w0 + h0.y * w1 + h0.z * w2 + h0.w * w3;
    acc1 += h1.x * w0 + h1.y * w1 + h1.z * w2 + h1.w * w3;
    acc2 += h2.x * w0 + h2.y * w1 + h2.z * w2 + h2.w * w3;
    acc3 += h3.x * w0 + h3.y * w1 + h3.z * w2 + h3.w * w3;
  }

  const float alo = av[c] * LOG2E, ahi = av[OUTD + c] * LOG2E;
  float pa0 = acc0 * alo, pa1 = acc1 * alo, pa2 = acc2 * alo, pa3 = acc3 * alo;
  float pb0 = acc0 * ahi, pb1 = acc1 * ahi, pb2 = acc2 * ahi, pb3 = acc3 * ahi;
#pragma unroll
  for (int off = 32; off >= 1; off >>= 1) {
    pa0 += __shfl_xor(pa0, off); pa1 += __shfl_xor(pa1, off);
    pa2 += __shfl_xor(pa2, off); pa3 += __shfl_xor(pa3, off);
    pb0 += __shfl_xor(pb0, off); pb1 += __shfl_xor(pb1, off);
    pb2 += __shfl_xor(pb2, off); pb3 += __shfl_xor(pb3, off);
  }
  const int ibase = i0 + wv * 4;
  if (c == 0) {
    float* sa = sA + rel * NN + ibase;
    float* sb = sB + rel * NN + ibase;
    sa[0] = pa0; sa[1] = pa1; sa[2] = pa2; sa[3] = pa3;
    sb[0] = pb0; sb[1] = pb1; sb[2] = pb2; sb[3] = pb3;
  }

  // 4 consecutive nodes land inside one 8-node block: single 8B store
  unsigned long long packed =
      (unsigned long long)f2bf(acc0)        | ((unsigned long long)f2bf(acc1) << 16) |
      ((unsigned long long)f2bf(acc2) << 32) | ((unsigned long long)f2bf(acc3) << 48);
  *(unsigned long long*)(whF + ((size_t)(rel * 512 + (ibase >> 3)) * 64 + c) * 8 + (ibase & 7)) = packed;
}

// ---------------- Kernel 2 (fused): single pass over A, coalesced j-major reads,
// e -> LDS w-tile in MFMA fragment order (XOR-swizzled), MFMA numerator + ones-MFMA denominator.
__global__ __launch_bounds__(512, 4) void gat_fused(
    const int* __restrict__ A0, const int* __restrict__ A1,
    const unsigned short* __restrict__ whF,
    const float* __restrict__ sA, const float* __restrict__ sB,
    float* __restrict__ numer,          // [2][ns][4096][64]
    float* __restrict__ denom,          // [2][ns][4096]
    int ns)
{
  __shared__ char lds[65536];           // 8 waves x 8 KB w-tile; red/dred aliased post-MFMA
  const int rel  = blockIdx.y;
  const int sp   = blockIdx.z;
  const int i0   = blockIdx.x * 16;
  const int t    = threadIdx.x;
  const int w    = t >> 6;
  const int lane = t & 63;
  const int quad = lane >> 4;
  const int m    = lane & 15;
  const int* __restrict__ A = rel ? A1 : A0;
  const unsigned short* __restrict__ wh = whF + (size_t)rel * 512 * 64 * 8;
  const float* __restrict__ sbp = sB + rel * NN;

  char* slice = lds + w * 8192;
  const int ql    = (lane >> 1) & 3;                          // quad of this lane's j's
  const int wbase = (lane >> 3) * 1024 + ql * 256 + (lane & 1) * 8;
  const int rbase = (quad * 16 + (m ^ quad)) * 16;            // frag-read slot (swizzle-matched)

  const float siv = sA[rel * NN + i0 + m];                    // lane r<16 holds s_i of row r

  floatx4 acc0 = {0.f,0.f,0.f,0.f}, acc1 = acc0, acc2 = acc0, acc3 = acc0, acc4 = acc0;
  bf16x8 vone;
#pragma unroll
  for (int k = 0; k < 8; k++) vone[k] = (__bf16)1.0f;

  const int nwin = (ns == 2) ? 1 : 2;                         // 256-j windows per wave
  for (int win = 0; win < nwin; win++) {
    const int jw = sp * (NN / ns) + (w * nwin + win) * 256;
    float4 sjv = *(const float4*)(sbp + jw + lane * 4);       // this lane's 4 s_j

    // ---- stage e into LDS w-tile (2 halves of 8 rows; batched coalesced A loads)
#pragma unroll
    for (int half = 0; half < 2; half++) {
      int4 av[8];
      const int* pA = A + (size_t)(i0 + half * 8) * NN + jw + lane * 4;
#pragma unroll
      for (int r = 0; r < 8; r++) av[r] = *(const int4*)(pA + (size_t)r * NN);
#pragma unroll
      for (int r = 0; r < 8; r++) {
        const int rr = half * 8 + r;
        const float si = __uint_as_float(__builtin_amdgcn_readlane(__float_as_uint(siv), rr));
        float t0 = si + sjv.x, t1 = si + sjv.y, t2 = si + sjv.z, t3 = si + sjv.w;
        float e0 = EXP2(fmaxf(t0, 0.2f * t0));
        float e1 = EXP2(fmaxf(t1, 0.2f * t1));
        float e2 = EXP2(fmaxf(t2, 0.2f * t2));
        float e3 = EXP2(fmaxf(t3, 0.2f * t3));
        e0 = av[r].x ? e0 : 0.f;
        e1 = av[r].y ? e1 : 0.f;
        e2 = av[r].z ? e2 : 0.f;
        e3 = av[r].w ? e3 : 0.f;
        uint2 pk;
        pk.x = (unsigned)f2bf(e0) | ((unsigned)f2bf(e1) << 16);
        pk.y = (unsigned)f2bf(e2) | ((unsigned)f2bf(e3) << 16);
        *(uint2*)(slice + wbase + ((rr ^ ql) << 4)) = pk;     // conflict-free (swizzled)
      }
    }

    // ---- MFMA over 8 K-steps; B-frags lane-contiguous from fragment-major whF (L2)
    const unsigned short* bb = wh + (size_t)(jw >> 3) * 512 + (size_t)m * 8;
#pragma unroll
    for (int ks = 0; ks < 8; ks++) {
      bf16x8 a = *(const bf16x8*)(slice + ks * 1024 + rbase);
      const unsigned short* bq = bb + (size_t)(ks * 4 + quad) * 512;
      bf16x8 b0 = *(const bf16x8*)(bq + 0 * 128);
      bf16x8 b1 = *(const bf16x8*)(bq + 1 * 128);
      bf16x8 b2 = *(const bf16x8*)(bq + 2 * 128);
      bf16x8 b3 = *(const bf16x8*)(bq + 3 * 128);
      acc0 = __builtin_amdgcn_mfma_f32_16x16x32_bf16(a, b0, acc0, 0, 0, 0);
      acc1 = __builtin_amdgcn_mfma_f32_16x16x32_bf16(a, b1, acc1, 0, 0, 0);
      acc2 = __builtin_amdgcn_mfma_f32_16x16x32_bf16(a, b2, acc2, 0, 0, 0);
      acc3 = __builtin_amdgcn_mfma_f32_16x16x32_bf16(a, b3, acc3, 0, 0, 0);
      acc4 = __builtin_amdgcn_mfma_f32_16x16x32_bf16(a, vone, acc4, 0, 0, 0);  // row sums
    }
  }

  // ---- epilogue into this wave's own (now dead) tile slice
  float* redw  = (float*)slice;                 // 1024 floats
  float* dredw = (float*)(slice + 4096);        // 16 floats
  // C/D layout: col = lane&15 (+16*nt), row = quad*4 + reg   [m89/m91]
#pragma unroll
  for (int r = 0; r < 4; r++) {
    const int row = quad * 4 + r;
    redw[row * 64 + 0 * 16 + m] = acc0[r];
    redw[row * 64 + 1 * 16 + m] = acc1[r];
    redw[row * 64 + 2 * 16 + m] = acc2[r];
    redw[row * 64 + 3 * 16 + m] = acc3[r];
  }
  if (m == 0) {
#pragma unroll
    for (int r = 0; r < 4; r++) dredw[quad * 4 + r] = acc4[r];
  }
  __syncthreads();

  const int c  = t & 63;
  const int r0 = t >> 6;
  const size_t base = ((size_t)rel * ns + sp) * NN;
#pragma unroll
  for (int rr = r0; rr < 16; rr += 8) {
    float nsum = 0.f, ds = 0.f;
#pragma unroll
    for (int ww = 0; ww < 8; ww++) {
      nsum += ((const float*)(lds + ww * 8192))[rr * 64 + c];
      ds   += ((const float*)(lds + ww * 8192 + 4096))[rr];
    }
    numer[(base + i0 + rr) * OUTD + c] = nsum;
    if (c == 0) denom[base + i0 + rr] = ds;
  }
}

// ---------------- Kernel 3: out = sum_rel( sum_sp(n) / sum_sp(d) ) + bias
__global__ __launch_bounds__(256) void gat_combine(
    const float* __restrict__ numer, const float* __restrict__ denom,
    const float* __restrict__ bias, float* __restrict__ out, int ns)
{
  const int idx = blockIdx.x * 256 + threadIdx.x;  // float4 index, 65536 total
  const int i  = idx >> 4;
  const int c4 = idx & 15;
  const float4* nv = (const float4*)numer;

  float4 o = ((const float4*)bias)[c4];
#pragma unroll
  for (int rel = 0; rel < 2; rel++) {
    float4 n = {0.f, 0.f, 0.f, 0.f};
    float  d = 0.f;
    for (int s = 0; s < ns; s++) {
      const size_t base = ((size_t)rel * ns + s) * NN + i;
      float4 np = nv[base * 16 + c4];
      n.x += np.x; n.y += np.y; n.z += np.z; n.w += np.w;
      d += denom[base];
    }
    float inv = d > 0.f ? 1.f / d : 0.f;   // isolated-row nan_to_num -> 0
    o.x += n.x * inv; o.y += n.y * inv; o.z += n.z * inv; o.w += n.w * inv;
  }
  ((float4*)out)[idx] = o;
}

extern "C" void kernel_launch(void* const* d_in, const int* in_sizes, int n_in,
                              void* d_out, int out_size, void* d_ws, size_t ws_size,
                              hipStream_t stream) {
  const float* H    = (const float*)d_in[0];
  const int*   A0   = (const int*)d_in[1];
  const int*   A1   = (const int*)d_in[2];
  const float* W0   = (const float*)d_in[3];
  const float* W1   = (const float*)d_in[4];
  const float* av0  = (const float*)d_in[5];
  const float* av1  = (const float*)d_in[6];
  const float* bias = (const float*)d_in[7];
  float* out = (float*)d_out;

  // ws layout: whF 1 MB | sA 32 KB | sB 32 KB | numer [2][ns][4096][64] | denom [2][ns][4096]
  const size_t whF_b = (size_t)2 * 512 * 64 * 8 * 2;     // 1 MB
  const size_t s_b   = (size_t)2 * NN * 4;               // 32 KB each
  const size_t need2 = whF_b + 2 * s_b + (size_t)2 * 2 * NN * OUTD * 4 + (size_t)2 * 2 * NN * 4;
  const int ns = (ws_size >= need2) ? 2 : 1;

  unsigned short* whF   = (unsigned short*)d_ws;
  float*          sA    = (float*)((char*)d_ws + whF_b);
  float*          sB    = (float*)((char*)d_ws + whF_b + s_b);
  float*          numer = (float*)((char*)d_ws + whF_b + 2 * s_b);
  float*          denom = numer + (size_t)2 * ns * NN * OUTD;

  gat_prep<<<dim3(NN / 16, 2), 256, 0, stream>>>(H, W0, W1, av0, av1, whF, sA, sB);
  gat_fused<<<dim3(NN / 16, 2, ns), 512, 0, stream>>>(A0, A1, whF, sA, sB, numer, denom, ns);
  gat_combine<<<(NN * OUTD / 4) / 256, 256, 0, stream>>>(numer, denom, bias, out, ns);
}